// Round 1
// baseline (253.501 us; speedup 1.0000x reference)
//
#include <hip/hip_runtime.h>

typedef __bf16 bf16;
typedef __bf16 bf16x8 __attribute__((ext_vector_type(8)));
typedef float f32x4 __attribute__((ext_vector_type(4)));

#define VOCAB 32000
#define HID 512
#define BATCH 128
#define SEQ 64

__device__ inline bf16x8 cvt8(float4 a, float4 b) {
  bf16x8 r;
  r[0] = (bf16)a.x; r[1] = (bf16)a.y; r[2] = (bf16)a.z; r[3] = (bf16)a.w;
  r[4] = (bf16)b.x; r[5] = (bf16)b.y; r[6] = (bf16)b.z; r[7] = (bf16)b.w;
  return r;
}

__device__ inline float fast_tanh(float x) {
  x = fminf(fmaxf(x, -15.f), 15.f);
  float e = __expf(2.f * x);
  return (e - 1.f) / (e + 1.f);
}
__device__ inline float fast_sig(float x) {
  return 1.f / (1.f + __expf(-x));
}

// ---------------------------------------------------------------------------
// Kernel 1: e1[b,h] = h0[b,:] . attn_W[h, 0:512] + attn_b[h]  (fp32)
//           + pack W2 = attn_W[:, 512:1024] into bf16 MFMA-B-operand order:
//           W2p[((kchunk*32 + ntile)*64 + lane)*8 + j], lane = klane*16+nlane
// ---------------------------------------------------------------------------
__global__ __launch_bounds__(512) void k_prep(
    const float* __restrict__ h0, const float* __restrict__ attn_W,
    const float* __restrict__ attn_b, bf16* __restrict__ W2p,
    float* __restrict__ e1) {
  int b = blockIdx.x, tid = threadIdx.x;
  __shared__ float h0s[512];
  h0s[tid] = h0[b * 512 + tid];
  __syncthreads();
  int h = tid;
  const float* wrow = attn_W + (size_t)h * 1024;
  float acc = attn_b[h];
#pragma unroll 4
  for (int d = 0; d < 512; d += 4) {
    float4 wv = *(const float4*)(wrow + d);
    float4 hv = *(const float4*)(&h0s[d]);
    acc += hv.x * wv.x + hv.y * wv.y + hv.z * wv.z + hv.w * wv.w;
  }
  e1[b * 512 + h] = acc;

  int gid = b * 512 + tid;  // one 8-element k-group of W2 per thread
  if (gid < 512 * 64) {
    int hh = gid >> 6, kc8 = gid & 63;  // row h, which 8-group of d
    const float* src = attn_W + (size_t)hh * 1024 + 512 + kc8 * 8;
    bf16x8 v = cvt8(((const float4*)src)[0], ((const float4*)src)[1]);
    int kchunk = kc8 >> 2, klane = kc8 & 3;
    int ntile = hh >> 4, nlane = hh & 15;
    int lane = klane * 16 + nlane;
    *(bf16x8*)(W2p + ((size_t)(kchunk * 32 + ntile) * 64 + lane) * 8) = v;
  }
}

// ---------------------------------------------------------------------------
// Kernel 2: per-batch fused attention. One block per b (512 thr = 8 waves).
//   E2[s,h] = enc[b] @ W2^T (bf16 MFMA), scores[s] = sum_h v[h]*tanh(E2+e1),
//   softmax over s, context[h] = sum_s w[s] enc[b,s,h],
//   A_cat[b] = bf16([emb[ids[b]] | context | h0[b]]).  Also zeroes gates_ws.
// ---------------------------------------------------------------------------
__global__ __launch_bounds__(512) void k_attn(
    const float* __restrict__ enc, const bf16* __restrict__ W2p,
    const float* __restrict__ e1, const float* __restrict__ vvec,
    const float* __restrict__ emb, const int* __restrict__ ids,
    const float* __restrict__ h0, bf16* __restrict__ Acat,
    float* __restrict__ gates_ws) {
  __shared__ char smem[65536];
  bf16* encA = (bf16*)smem;                 // phase 1: 64x512 bf16 (swizzled)
  float* spart = (float*)smem;              // phase 2: 8x64
  float* wgt = (float*)(smem + 2048);       // 64
  float* ctxp = (float*)(smem + 2304);      // 8x512

  int b = blockIdx.x, tid = threadIdx.x;
  int w = tid >> 6, lane = tid & 63;
  int l15 = lane & 15, lq = lane >> 4;
  const float* encb = enc + (size_t)b * SEQ * HID;

  // zero the gates accumulator (one float4 per thread over 128 blocks)
  {
    int gid = b * 512 + tid;
    float4 z = {0.f, 0.f, 0.f, 0.f};
    ((float4*)gates_ws)[gid] = z;
  }

  // stage enc[b] -> bf16 LDS, 16B chunks XOR-swizzled by row for bank spread
#pragma unroll
  for (int i = 0; i < 8; ++i) {
    int cl = tid + i * 512;        // chunk id 0..4095
    int row = cl >> 6;             // s
    int c = cl & 63;               // logical chunk in row
    int phys = c ^ (row & 7);
    const float4* src = (const float4*)(encb + row * 512 + c * 8);
    bf16x8 v = cvt8(src[0], src[1]);
    *(bf16x8*)(encA + row * 512 + phys * 8) = v;
  }
  __syncthreads();

  // MFMA K-loop: wave w covers ntiles w*4..w*4+3 (h 64), all 4 mtiles (s 64)
  f32x4 acc[4][4];
#pragma unroll
  for (int mt = 0; mt < 4; ++mt)
#pragma unroll
    for (int jn = 0; jn < 4; ++jn) acc[mt][jn] = (f32x4)0.f;

  for (int kc = 0; kc < 16; ++kc) {
    bf16x8 bfr[4], af[4];
#pragma unroll
    for (int jn = 0; jn < 4; ++jn) {
      int nt = w * 4 + jn;
      bfr[jn] = *(const bf16x8*)(W2p + ((size_t)(kc * 32 + nt) * 64 + lane) * 8);
    }
#pragma unroll
    for (int mt = 0; mt < 4; ++mt) {
      int row = mt * 16 + l15;
      int c = kc * 4 + lq;
      int phys = c ^ (row & 7);
      af[mt] = *(const bf16x8*)(encA + row * 512 + phys * 8);
    }
#pragma unroll
    for (int mt = 0; mt < 4; ++mt)
#pragma unroll
      for (int jn = 0; jn < 4; ++jn)
        acc[mt][jn] = __builtin_amdgcn_mfma_f32_16x16x32_bf16(
            af[mt], bfr[jn], acc[mt][jn], 0, 0, 0);
  }
  __syncthreads();  // encA dead; smem reused below

  // epilogue: p[mt][reg] = sum over this wave's 64 h of v[h]*tanh(E2+e1)
  float p[4][4];
#pragma unroll
  for (int mt = 0; mt < 4; ++mt)
#pragma unroll
    for (int r = 0; r < 4; ++r) p[mt][r] = 0.f;
#pragma unroll
  for (int jn = 0; jn < 4; ++jn) {
    int h = (w * 4 + jn) * 16 + l15;
    float e1v = e1[b * 512 + h];
    float vv = vvec[h];
#pragma unroll
    for (int mt = 0; mt < 4; ++mt)
#pragma unroll
      for (int r = 0; r < 4; ++r)
        p[mt][r] += vv * fast_tanh(acc[mt][jn][r] + e1v);
  }
#pragma unroll
  for (int mt = 0; mt < 4; ++mt)
#pragma unroll
    for (int r = 0; r < 4; ++r) {
      float x = p[mt][r];
      x += __shfl_xor(x, 1);
      x += __shfl_xor(x, 2);
      x += __shfl_xor(x, 4);
      x += __shfl_xor(x, 8);
      p[mt][r] = x;
    }
  if (l15 == 0) {
#pragma unroll
    for (int mt = 0; mt < 4; ++mt)
#pragma unroll
      for (int r = 0; r < 4; ++r) {
        int s = mt * 16 + lq * 4 + r;
        spart[w * 64 + s] = p[mt][r];
      }
  }
  __syncthreads();

  // softmax over s (wave 0)
  if (tid < 64) {
    float sc = 0.f;
#pragma unroll
    for (int ww = 0; ww < 8; ++ww) sc += spart[ww * 64 + tid];
    float mx = sc;
    for (int m = 32; m; m >>= 1) mx = fmaxf(mx, __shfl_xor(mx, m));
    float e = __expf(sc - mx);
    float sm = e;
    for (int m = 32; m; m >>= 1) sm += __shfl_xor(sm, m);
    wgt[tid] = e / sm;
  }
  __syncthreads();

  // context: thread = (sgroup of 8 s, h-chunk of 8); read enc from global (L2)
  {
    int hc = tid & 63, sg = tid >> 6;
    float a8[8];
#pragma unroll
    for (int j = 0; j < 8; ++j) a8[j] = 0.f;
    for (int s = sg * 8; s < sg * 8 + 8; ++s) {
      float wv = wgt[s];
      const float4* src = (const float4*)(encb + s * 512 + hc * 8);
      float4 x0 = src[0], x1 = src[1];
      a8[0] += wv * x0.x; a8[1] += wv * x0.y; a8[2] += wv * x0.z; a8[3] += wv * x0.w;
      a8[4] += wv * x1.x; a8[5] += wv * x1.y; a8[6] += wv * x1.z; a8[7] += wv * x1.w;
    }
#pragma unroll
    for (int j = 0; j < 8; ++j) ctxp[sg * 512 + hc * 8 + j] = a8[j];
  }
  __syncthreads();

  // reduce context + write A_cat row
  {
    int h = tid;
    float c = 0.f;
#pragma unroll
    for (int g = 0; g < 8; ++g) c += ctxp[g * 512 + h];
    int id = ids[b];
    Acat[(size_t)b * 1536 + h] = (bf16)emb[(size_t)id * 512 + h];
    Acat[(size_t)b * 1536 + 512 + h] = (bf16)c;
    Acat[(size_t)b * 1536 + 1024 + h] = (bf16)h0[b * 512 + h];
  }
}

// ---------------------------------------------------------------------------
// Kernel 3: gates partial GEMM. grid (16 n-tiles, 6 k-splits).
//   gates[b, n] += A_cat[b, k] * W[n, k]  over this block's K range (256).
//   W = W_ih cols 0..1023, W_hh cols 1024..1535. fp32 atomicAdd into ws.
// ---------------------------------------------------------------------------
__global__ __launch_bounds__(512) void k_gates(
    const bf16* __restrict__ Acat, const float* __restrict__ W_ih,
    const float* __restrict__ W_hh, float* __restrict__ gates_ws) {
  int nb = blockIdx.x, ks = blockIdx.y;
  __shared__ bf16 Wl[128 * 40];
  int tid = threadIdx.x, w = tid >> 6, lane = tid & 63;
  int l15 = lane & 15, lq = lane >> 4;
  int wrow = w & 3, wcol = w >> 2;
  f32x4 acc[2][4];
#pragma unroll
  for (int i = 0; i < 2; ++i)
#pragma unroll
    for (int j = 0; j < 4; ++j) acc[i][j] = (f32x4)0.f;

  for (int kt = 0; kt < 8; ++kt) {
    int kb = ks * 256 + kt * 32;
    {
      int r = tid >> 2, sub = tid & 3;
      int grow = nb * 128 + r;
      const float* src = (kb < 1024)
                             ? (W_ih + (size_t)grow * 1024 + kb + sub * 8)
                             : (W_hh + (size_t)grow * 512 + (kb - 1024) + sub * 8);
      bf16x8 v = cvt8(((const float4*)src)[0], ((const float4*)src)[1]);
      *(bf16x8*)(Wl + r * 40 + sub * 8) = v;
    }
    __syncthreads();
    bf16x8 af[2], bfr[4];
#pragma unroll
    for (int mi = 0; mi < 2; ++mi) {
      int m = (wrow * 2 + mi) * 16 + l15;
      af[mi] = *(const bf16x8*)(Acat + (size_t)m * 1536 + kb + lq * 8);
    }
#pragma unroll
    for (int jn = 0; jn < 4; ++jn) {
      int nt = wcol * 4 + jn;
      bfr[jn] = *(const bf16x8*)(Wl + (nt * 16 + l15) * 40 + lq * 8);
    }
#pragma unroll
    for (int mi = 0; mi < 2; ++mi)
#pragma unroll
      for (int jn = 0; jn < 4; ++jn)
        acc[mi][jn] = __builtin_amdgcn_mfma_f32_16x16x32_bf16(
            af[mi], bfr[jn], acc[mi][jn], 0, 0, 0);
    __syncthreads();
  }
#pragma unroll
  for (int mi = 0; mi < 2; ++mi)
#pragma unroll
    for (int jn = 0; jn < 4; ++jn)
#pragma unroll
      for (int r = 0; r < 4; ++r) {
        int bb = (wrow * 2 + mi) * 16 + lq * 4 + r;
        int n = nb * 128 + wcol * 64 + jn * 16 + l15;
        atomicAdd(&gates_ws[(size_t)bb * 2048 + n], acc[mi][jn][r]);
      }
}

// ---------------------------------------------------------------------------
// Kernel 4: elementwise LSTM cell. Writes h_new, c_new to d_out + bf16 copy.
// ---------------------------------------------------------------------------
__global__ __launch_bounds__(512) void k_cell(
    const float* __restrict__ gates_ws, const float* __restrict__ b_ih,
    const float* __restrict__ b_hh, const float* __restrict__ c0,
    float* __restrict__ out, bf16* __restrict__ hnewb) {
  int idx = blockIdx.x * 512 + threadIdx.x;  // 0..65535
  int b = idx >> 9, h = idx & 511;
  const float* g = gates_ws + (size_t)b * 2048;
  float iv = g[h] + b_ih[h] + b_hh[h];
  float fv = g[512 + h] + b_ih[512 + h] + b_hh[512 + h];
  float gv = g[1024 + h] + b_ih[1024 + h] + b_hh[1024 + h];
  float ov = g[1536 + h] + b_ih[1536 + h] + b_hh[1536 + h];
  float cn = fast_sig(fv) * c0[idx] + fast_sig(iv) * fast_tanh(gv);
  float hn = fast_sig(ov) * fast_tanh(cn);
  out[4096000 + idx] = hn;
  out[4096000 + 65536 + idx] = cn;
  hnewb[idx] = (bf16)hn;
}

// ---------------------------------------------------------------------------
// Kernel 5: FC. pred[b, v] = h_new[b,:] . fc_W[v,:] + fc_b[v].
// 250 blocks of 128 vocab rows; fc_W converted fp32->bf16 inline (read once).
// ---------------------------------------------------------------------------
__global__ __launch_bounds__(512) void k_fc(
    const bf16* __restrict__ hnewb, const float* __restrict__ fc_W,
    const float* __restrict__ fc_b, float* __restrict__ out) {
  int nb = blockIdx.x;  // 0..249
  int vb = nb * 128;
  __shared__ bf16 Wl[128 * 40];
  int tid = threadIdx.x, w = tid >> 6, lane = tid & 63;
  int l15 = lane & 15, lq = lane >> 4;
  int wrow = w & 3, wcol = w >> 2;
  f32x4 acc[2][4];
#pragma unroll
  for (int i = 0; i < 2; ++i)
#pragma unroll
    for (int j = 0; j < 4; ++j) acc[i][j] = (f32x4)0.f;

  for (int kt = 0; kt < 16; ++kt) {
    int kb = kt * 32;
    {
      int r = tid >> 2, sub = tid & 3;
      const float* src = fc_W + (size_t)(vb + r) * 512 + kb + sub * 8;
      bf16x8 v = cvt8(((const float4*)src)[0], ((const float4*)src)[1]);
      *(bf16x8*)(Wl + r * 40 + sub * 8) = v;
    }
    __syncthreads();
    bf16x8 af[2], bfr[4];
#pragma unroll
    for (int mi = 0; mi < 2; ++mi) {
      int m = (wrow * 2 + mi) * 16 + l15;
      af[mi] = *(const bf16x8*)(hnewb + (size_t)m * 512 + kb + lq * 8);
    }
#pragma unroll
    for (int jn = 0; jn < 4; ++jn) {
      int nt = wcol * 4 + jn;
      bfr[jn] = *(const bf16x8*)(Wl + (nt * 16 + l15) * 40 + lq * 8);
    }
#pragma unroll
    for (int mi = 0; mi < 2; ++mi)
#pragma unroll
      for (int jn = 0; jn < 4; ++jn)
        acc[mi][jn] = __builtin_amdgcn_mfma_f32_16x16x32_bf16(
            af[mi], bfr[jn], acc[mi][jn], 0, 0, 0);
    __syncthreads();
  }
#pragma unroll
  for (int mi = 0; mi < 2; ++mi)
#pragma unroll
    for (int jn = 0; jn < 4; ++jn) {
      int vv = vb + wcol * 64 + jn * 16 + l15;
      float bias = fc_b[vv];
#pragma unroll
      for (int r = 0; r < 4; ++r) {
        int bb = (wrow * 2 + mi) * 16 + lq * 4 + r;
        out[(size_t)bb * 32000 + vv] = acc[mi][jn][r] + bias;
      }
    }
}

extern "C" void kernel_launch(void* const* d_in, const int* in_sizes, int n_in,
                              void* d_out, int out_size, void* d_ws,
                              size_t ws_size, hipStream_t stream) {
  const int* ids = (const int*)d_in[0];
  const float* h0 = (const float*)d_in[1];
  const float* c0 = (const float*)d_in[2];
  const float* enc = (const float*)d_in[3];
  const float* emb = (const float*)d_in[4];
  const float* attn_W = (const float*)d_in[5];
  const float* attn_b = (const float*)d_in[6];
  const float* vvec = (const float*)d_in[7];
  const float* W_ih = (const float*)d_in[8];
  const float* W_hh = (const float*)d_in[9];
  const float* b_ih = (const float*)d_in[10];
  const float* b_hh = (const float*)d_in[11];
  const float* fc_W = (const float*)d_in[12];
  const float* fc_b = (const float*)d_in[13];
  float* out = (float*)d_out;
  char* ws = (char*)d_ws;

  bf16* W2p = (bf16*)ws;                    // 512*512*2     = 524288
  float* e1 = (float*)(ws + 524288);        // 128*512*4     = 262144
  bf16* Acat = (bf16*)(ws + 786432);        // 128*1536*2    = 393216
  bf16* hnewb = (bf16*)(ws + 1179648);      // 128*512*2     = 131072
  float* gates = (float*)(ws + 1310720);    // 128*2048*4    = 1048576

  k_prep<<<128, 512, 0, stream>>>(h0, attn_W, attn_b, W2p, e1);
  k_attn<<<128, 512, 0, stream>>>(enc, W2p, e1, vvec, emb, ids, h0, Acat, gates);
  k_gates<<<dim3(16, 6), 512, 0, stream>>>(Acat, W_ih, W_hh, gates);
  k_cell<<<128, 512, 0, stream>>>(gates, b_ih, b_hh, c0, out, hnewb);
  k_fc<<<250, 512, 0, stream>>>(hnewb, fc_W, fc_b, out);
}

// Round 2
// 226.469 us; speedup vs baseline: 1.1194x; 1.1194x over previous
//
#include <hip/hip_runtime.h>

typedef __bf16 bf16;
typedef __bf16 bf16x8 __attribute__((ext_vector_type(8)));
typedef __bf16 bf16x4 __attribute__((ext_vector_type(4)));
typedef float f32x4 __attribute__((ext_vector_type(4)));

#define VOCAB 32000
#define HID 512
#define BATCH 128
#define SEQ 64

__device__ inline bf16x8 cvt8(float4 a, float4 b) {
  bf16x8 r;
  r[0] = (bf16)a.x; r[1] = (bf16)a.y; r[2] = (bf16)a.z; r[3] = (bf16)a.w;
  r[4] = (bf16)b.x; r[5] = (bf16)b.y; r[6] = (bf16)b.z; r[7] = (bf16)b.w;
  return r;
}
__device__ inline bf16x4 cvt4(float4 a) {
  bf16x4 r;
  r[0] = (bf16)a.x; r[1] = (bf16)a.y; r[2] = (bf16)a.z; r[3] = (bf16)a.w;
  return r;
}

__device__ inline float fast_tanh(float x) {
  x = fminf(fmaxf(x, -15.f), 15.f);
  float e = __expf(2.f * x);
  return (e - 1.f) / (e + 1.f);
}
__device__ inline float fast_sig(float x) {
  return 1.f / (1.f + __expf(-x));
}

// ---------------------------------------------------------------------------
// Kernel 1: pack FULL attn_W (512 x 1024 fp32) -> bf16 MFMA-B-operand order.
//   attn_W col k -> kchunk = k>>5; Wp[((kchunk*32 + ntile)*64 + lane)*8 + j],
//   lane = klane*16 + nlane, ntile = h>>4, nlane = h&15, klane = (k>>3)&3.
//   Fully coalesced: 128 consecutive threads read one 4 KB row.
// ---------------------------------------------------------------------------
__global__ __launch_bounds__(512) void k_pack(
    const float* __restrict__ attn_W, bf16* __restrict__ Wp) {
  int gid = blockIdx.x * 512 + threadIdx.x;  // 0..65535
  int hh = gid >> 7;                         // 0..511 (row h)
  int kc8 = gid & 127;                       // which 8-group of k (0..127)
  const float* src = attn_W + (size_t)hh * 1024 + kc8 * 8;
  bf16x8 v = cvt8(((const float4*)src)[0], ((const float4*)src)[1]);
  int kchunk = kc8 >> 2, klane = kc8 & 3;
  int ntile = hh >> 4, nlane = hh & 15;
  int lane = klane * 16 + nlane;
  *(bf16x8*)(Wp + ((size_t)(kchunk * 32 + ntile) * 64 + lane) * 8) = v;
}

// ---------------------------------------------------------------------------
// Kernel 2: per-batch fused attention, e1 folded in. One block per b.
//   energy[s,h] = tanh( h0[b]·W1^T[h] + enc[b,s]·W2^T[h] + attn_b[h] )
//   via K=1024 MFMA; the h0 half accumulates in acc_e1 (row-invariant).
//   scores -> softmax -> context -> A_cat[b] = bf16([emb|ctx|h0]).
//   Also zeroes gates_ws.
// ---------------------------------------------------------------------------
__global__ __launch_bounds__(512) void k_attn(
    const float* __restrict__ enc, const bf16* __restrict__ Wp,
    const float* __restrict__ attn_b, const float* __restrict__ vvec,
    const float* __restrict__ emb, const int* __restrict__ ids,
    const float* __restrict__ h0, bf16* __restrict__ Acat,
    float* __restrict__ gates_ws) {
  __shared__ char smem[65536];
  __shared__ bf16 h0s[512];
  bf16* encA = (bf16*)smem;                 // phase 1: 64x512 bf16 (swizzled)
  float* spart = (float*)smem;              // phase 2: 8x64
  float* wgt = (float*)(smem + 2048);       // 64
  float* ctxp = (float*)(smem + 2304);      // 8x512

  int b = blockIdx.x, tid = threadIdx.x;
  int w = tid >> 6, lane = tid & 63;
  int l15 = lane & 15, lq = lane >> 4;
  const float* encb = enc + (size_t)b * SEQ * HID;

  // zero the gates accumulator (one float4 per thread over 128 blocks)
  {
    int gid = b * 512 + tid;
    float4 z = {0.f, 0.f, 0.f, 0.f};
    ((float4*)gates_ws)[gid] = z;
  }

  h0s[tid] = (bf16)h0[b * 512 + tid];

  // stage enc[b] -> bf16 LDS, 16B chunks XOR-swizzled by row for bank spread
#pragma unroll
  for (int i = 0; i < 8; ++i) {
    int cl = tid + i * 512;        // chunk id 0..4095
    int row = cl >> 6;             // s
    int c = cl & 63;               // logical chunk in row
    int phys = c ^ (row & 7);
    const float4* src = (const float4*)(encb + row * 512 + c * 8);
    bf16x8 v = cvt8(src[0], src[1]);
    *(bf16x8*)(encA + row * 512 + phys * 8) = v;
  }
  __syncthreads();

  f32x4 acc[4][4];
  f32x4 acc_e1[4];
#pragma unroll
  for (int mt = 0; mt < 4; ++mt)
#pragma unroll
    for (int jn = 0; jn < 4; ++jn) acc[mt][jn] = (f32x4)0.f;
#pragma unroll
  for (int jn = 0; jn < 4; ++jn) acc_e1[jn] = (f32x4)0.f;

  // h0 half: kchunks 0..15 (attn_W cols 0..511). A-frag = LDS broadcast.
#pragma unroll 4
  for (int kc = 0; kc < 16; ++kc) {
    bf16x8 af = *(const bf16x8*)(h0s + kc * 32 + lq * 8);
#pragma unroll
    for (int jn = 0; jn < 4; ++jn) {
      int nt = w * 4 + jn;
      bf16x8 bfr = *(const bf16x8*)(Wp + ((size_t)(kc * 32 + nt) * 64 + lane) * 8);
      acc_e1[jn] = __builtin_amdgcn_mfma_f32_16x16x32_bf16(af, bfr, acc_e1[jn], 0, 0, 0);
    }
  }

  // enc half: kchunks 16..31 (attn_W cols 512..1023)
#pragma unroll 2
  for (int kc = 16; kc < 32; ++kc) {
    bf16x8 bfr[4], af[4];
#pragma unroll
    for (int jn = 0; jn < 4; ++jn) {
      int nt = w * 4 + jn;
      bfr[jn] = *(const bf16x8*)(Wp + ((size_t)(kc * 32 + nt) * 64 + lane) * 8);
    }
#pragma unroll
    for (int mt = 0; mt < 4; ++mt) {
      int row = mt * 16 + l15;
      int c = (kc - 16) * 4 + lq;
      int phys = c ^ (row & 7);
      af[mt] = *(const bf16x8*)(encA + row * 512 + phys * 8);
    }
#pragma unroll
    for (int mt = 0; mt < 4; ++mt)
#pragma unroll
      for (int jn = 0; jn < 4; ++jn)
        acc[mt][jn] = __builtin_amdgcn_mfma_f32_16x16x32_bf16(
            af[mt], bfr[jn], acc[mt][jn], 0, 0, 0);
  }
  __syncthreads();  // encA dead; smem reused below

  // epilogue: p[mt][reg] = sum over this wave's 64 h of v[h]*tanh(energy)
  float p[4][4];
#pragma unroll
  for (int mt = 0; mt < 4; ++mt)
#pragma unroll
    for (int r = 0; r < 4; ++r) p[mt][r] = 0.f;
#pragma unroll
  for (int jn = 0; jn < 4; ++jn) {
    int h = (w * 4 + jn) * 16 + l15;
    float bias = attn_b[h];
    float vv = vvec[h];
#pragma unroll
    for (int mt = 0; mt < 4; ++mt)
#pragma unroll
      for (int r = 0; r < 4; ++r)
        p[mt][r] += vv * fast_tanh(acc[mt][jn][r] + acc_e1[jn][r] + bias);
  }
#pragma unroll
  for (int mt = 0; mt < 4; ++mt)
#pragma unroll
    for (int r = 0; r < 4; ++r) {
      float x = p[mt][r];
      x += __shfl_xor(x, 1);
      x += __shfl_xor(x, 2);
      x += __shfl_xor(x, 4);
      x += __shfl_xor(x, 8);
      p[mt][r] = x;
    }
  if (l15 == 0) {
#pragma unroll
    for (int mt = 0; mt < 4; ++mt)
#pragma unroll
      for (int r = 0; r < 4; ++r) {
        int s = mt * 16 + lq * 4 + r;
        spart[w * 64 + s] = p[mt][r];
      }
  }
  __syncthreads();

  // softmax over s (wave 0)
  if (tid < 64) {
    float sc = 0.f;
#pragma unroll
    for (int ww = 0; ww < 8; ++ww) sc += spart[ww * 64 + tid];
    float mx = sc;
    for (int m = 32; m; m >>= 1) mx = fmaxf(mx, __shfl_xor(mx, m));
    float e = __expf(sc - mx);
    float sm = e;
    for (int m = 32; m; m >>= 1) sm += __shfl_xor(sm, m);
    wgt[tid] = e / sm;
  }
  __syncthreads();

  // context: thread = (sgroup of 8 s, h-chunk of 8); enc re-read hits L2
  {
    int hc = tid & 63, sg = tid >> 6;
    float a8[8];
#pragma unroll
    for (int j = 0; j < 8; ++j) a8[j] = 0.f;
    for (int s = sg * 8; s < sg * 8 + 8; ++s) {
      float wv = wgt[s];
      const float4* src = (const float4*)(encb + s * 512 + hc * 8);
      float4 x0 = src[0], x1 = src[1];
      a8[0] += wv * x0.x; a8[1] += wv * x0.y; a8[2] += wv * x0.z; a8[3] += wv * x0.w;
      a8[4] += wv * x1.x; a8[5] += wv * x1.y; a8[6] += wv * x1.z; a8[7] += wv * x1.w;
    }
#pragma unroll
    for (int j = 0; j < 8; ++j) ctxp[sg * 512 + hc * 8 + j] = a8[j];
  }
  __syncthreads();

  // reduce context + write A_cat row
  {
    int h = tid;
    float c = 0.f;
#pragma unroll
    for (int g = 0; g < 8; ++g) c += ctxp[g * 512 + h];
    int id = ids[b];
    Acat[(size_t)b * 1536 + h] = (bf16)emb[(size_t)id * 512 + h];
    Acat[(size_t)b * 1536 + 512 + h] = (bf16)c;
    Acat[(size_t)b * 1536 + 1024 + h] = (bf16)h0[b * 512 + h];
  }
}

// ---------------------------------------------------------------------------
// Kernel 3: gates partial GEMM. grid (32 n-tiles of 64, 6 k-splits of 256).
//   gates[b, n] += A_cat[b, k] * W[n, k]; W = [W_ih cols | W_hh cols].
//   Register-prefetched staging; fp32 atomicAdd into ws.
// ---------------------------------------------------------------------------
__global__ __launch_bounds__(512) void k_gates(
    const bf16* __restrict__ Acat, const float* __restrict__ W_ih,
    const float* __restrict__ W_hh, float* __restrict__ gates_ws) {
  int nb = blockIdx.x, ks = blockIdx.y;
  __shared__ bf16 Wl[64 * 40];
  int tid = threadIdx.x, w = tid >> 6, lane = tid & 63;
  int l15 = lane & 15, lq = lane >> 4;
  int wrow = w & 3, wcol = w >> 2;  // wrow: 2 mtiles each; wcol: 2 ntiles
  int r = tid >> 3, sub = tid & 7;  // staging: 64 rows x 8 threads
  int grow = nb * 64 + r;

  f32x4 acc[2][2];
#pragma unroll
  for (int i = 0; i < 2; ++i)
#pragma unroll
    for (int j = 0; j < 2; ++j) acc[i][j] = (f32x4)0.f;

  auto load_tile = [&](int kt) -> float4 {
    int kb = ks * 256 + kt * 32;
    const float* src = (kb < 1024)
                           ? (W_ih + (size_t)grow * 1024 + kb + sub * 4)
                           : (W_hh + (size_t)grow * 512 + (kb - 1024) + sub * 4);
    return *(const float4*)src;
  };

  float4 pf = load_tile(0);
  for (int kt = 0; kt < 8; ++kt) {
    *(bf16x4*)(Wl + r * 40 + sub * 4) = cvt4(pf);
    __syncthreads();
    if (kt + 1 < 8) pf = load_tile(kt + 1);
    int kglob = ks * 256 + kt * 32;
    bf16x8 af[2], bfr[2];
#pragma unroll
    for (int mi = 0; mi < 2; ++mi) {
      int m = (wrow * 2 + mi) * 16 + l15;
      af[mi] = *(const bf16x8*)(Acat + (size_t)m * 1536 + kglob + lq * 8);
    }
#pragma unroll
    for (int jn = 0; jn < 2; ++jn) {
      int nt = wcol * 2 + jn;
      bfr[jn] = *(const bf16x8*)(Wl + (nt * 16 + l15) * 40 + lq * 8);
    }
#pragma unroll
    for (int mi = 0; mi < 2; ++mi)
#pragma unroll
      for (int jn = 0; jn < 2; ++jn)
        acc[mi][jn] = __builtin_amdgcn_mfma_f32_16x16x32_bf16(
            af[mi], bfr[jn], acc[mi][jn], 0, 0, 0);
    __syncthreads();
  }
#pragma unroll
  for (int mi = 0; mi < 2; ++mi)
#pragma unroll
    for (int jn = 0; jn < 2; ++jn)
#pragma unroll
      for (int rr = 0; rr < 4; ++rr) {
        int bb = (wrow * 2 + mi) * 16 + lq * 4 + rr;
        int n = nb * 64 + (wcol * 2 + jn) * 16 + l15;
        atomicAdd(&gates_ws[(size_t)bb * 2048 + n], acc[mi][jn][rr]);
      }
}

// ---------------------------------------------------------------------------
// Kernel 4: elementwise LSTM cell. Writes h_new, c_new to d_out + bf16 copy.
// ---------------------------------------------------------------------------
__global__ __launch_bounds__(512) void k_cell(
    const float* __restrict__ gates_ws, const float* __restrict__ b_ih,
    const float* __restrict__ b_hh, const float* __restrict__ c0,
    float* __restrict__ out, bf16* __restrict__ hnewb) {
  int idx = blockIdx.x * 512 + threadIdx.x;  // 0..65535
  int b = idx >> 9, h = idx & 511;
  const float* g = gates_ws + (size_t)b * 2048;
  float iv = g[h] + b_ih[h] + b_hh[h];
  float fv = g[512 + h] + b_ih[512 + h] + b_hh[512 + h];
  float gv = g[1024 + h] + b_ih[1024 + h] + b_hh[1024 + h];
  float ov = g[1536 + h] + b_ih[1536 + h] + b_hh[1536 + h];
  float cn = fast_sig(fv) * c0[idx] + fast_sig(iv) * fast_tanh(gv);
  float hn = fast_sig(ov) * fast_tanh(cn);
  out[4096000 + idx] = hn;
  out[4096000 + 65536 + idx] = cn;
  hnewb[idx] = (bf16)hn;
}

// ---------------------------------------------------------------------------
// Kernel 5: FC. pred[b, v] = h_new[b,:] . fc_W[v,:] + fc_b[v].
// 500 blocks x 64 vocab rows (2 blocks/CU for latency overlap);
// register-prefetched staging; fc_W converted fp32->bf16 inline (read once).
// ---------------------------------------------------------------------------
__global__ __launch_bounds__(512) void k_fc(
    const bf16* __restrict__ hnewb, const float* __restrict__ fc_W,
    const float* __restrict__ fc_b, float* __restrict__ out) {
  int vb = blockIdx.x * 64;
  __shared__ bf16 Wl[64 * 40];
  int tid = threadIdx.x, w = tid >> 6, lane = tid & 63;
  int l15 = lane & 15, lq = lane >> 4;
  int wrow = w & 3, wcol = w >> 2;
  int r = tid >> 3, sub = tid & 7;

  f32x4 acc[2][2];
#pragma unroll
  for (int i = 0; i < 2; ++i)
#pragma unroll
    for (int j = 0; j < 2; ++j) acc[i][j] = (f32x4)0.f;

  const float* wbase = fc_W + (size_t)(vb + r) * 512 + sub * 4;
  float4 pf = *(const float4*)(wbase);
  for (int kt = 0; kt < 16; ++kt) {
    *(bf16x4*)(Wl + r * 40 + sub * 4) = cvt4(pf);
    __syncthreads();
    if (kt + 1 < 16) pf = *(const float4*)(wbase + (kt + 1) * 32);
    int kb = kt * 32;
    bf16x8 af[2], bfr[2];
#pragma unroll
    for (int mi = 0; mi < 2; ++mi) {
      int m = (wrow * 2 + mi) * 16 + l15;
      af[mi] = *(const bf16x8*)(hnewb + (size_t)m * 512 + kb + lq * 8);
    }
#pragma unroll
    for (int jn = 0; jn < 2; ++jn) {
      int nt = wcol * 2 + jn;
      bfr[jn] = *(const bf16x8*)(Wl + (nt * 16 + l15) * 40 + lq * 8);
    }
#pragma unroll
    for (int mi = 0; mi < 2; ++mi)
#pragma unroll
      for (int jn = 0; jn < 2; ++jn)
        acc[mi][jn] = __builtin_amdgcn_mfma_f32_16x16x32_bf16(
            af[mi], bfr[jn], acc[mi][jn], 0, 0, 0);
    __syncthreads();
  }
#pragma unroll
  for (int mi = 0; mi < 2; ++mi)
#pragma unroll
    for (int jn = 0; jn < 2; ++jn) {
      int vv = vb + (wcol * 2 + jn) * 16 + l15;
      float bias = fc_b[vv];
#pragma unroll
      for (int rr = 0; rr < 4; ++rr) {
        int bb = (wrow * 2 + mi) * 16 + lq * 4 + rr;
        out[(size_t)bb * 32000 + vv] = acc[mi][jn][rr] + bias;
      }
    }
}

extern "C" void kernel_launch(void* const* d_in, const int* in_sizes, int n_in,
                              void* d_out, int out_size, void* d_ws,
                              size_t ws_size, hipStream_t stream) {
  const int* ids = (const int*)d_in[0];
  const float* h0 = (const float*)d_in[1];
  const float* c0 = (const float*)d_in[2];
  const float* enc = (const float*)d_in[3];
  const float* emb = (const float*)d_in[4];
  const float* attn_W = (const float*)d_in[5];
  const float* attn_b = (const float*)d_in[6];
  const float* vvec = (const float*)d_in[7];
  const float* W_ih = (const float*)d_in[8];
  const float* W_hh = (const float*)d_in[9];
  const float* b_ih = (const float*)d_in[10];
  const float* b_hh = (const float*)d_in[11];
  const float* fc_W = (const float*)d_in[12];
  const float* fc_b = (const float*)d_in[13];
  float* out = (float*)d_out;
  char* ws = (char*)d_ws;

  bf16* Wp = (bf16*)ws;                     // 512*1024*2    = 1048576
  bf16* Acat = (bf16*)(ws + 1048576);       // 128*1536*2    = 393216
  bf16* hnewb = (bf16*)(ws + 1441792);      // 128*512*2     = 131072
  float* gates = (float*)(ws + 1572864);    // 128*2048*4    = 1048576

  k_pack<<<128, 512, 0, stream>>>(attn_W, Wp);
  k_attn<<<128, 512, 0, stream>>>(enc, Wp, attn_b, vvec, emb, ids, h0, Acat, gates);
  k_gates<<<dim3(32, 6), 512, 0, stream>>>(Acat, W_ih, W_hh, gates);
  k_cell<<<128, 512, 0, stream>>>(gates, b_ih, b_hh, c0, out, hnewb);
  k_fc<<<500, 512, 0, stream>>>(hnewb, fc_W, fc_b, out);
}